// Round 9
// baseline (264.694 us; speedup 1.0000x reference)
//
#include <hip/hip_runtime.h>

#define N_NODES 50000
#define FEAT    128
#define NEDGE   600000

#define NBUK    196        // buckets per rel (256 dsts each); 588 total
#define NBUKT   588
#define BUKCAP  4096       // bucket total: mean 3061, sigma 55 -> 19 sigma
#define KPART   224        // partition slices per rel
#define NB_PART 672        // 3 rels x KPART, one rel per block
#define SEGCAP  44         // mean 13.7; Poisson tail @44 ~ 4e-11/seg, 5e-6 overall
#define SEGQ    11         // SEGCAP/4 uint4s
#define EPB     2679       // ceil(600000/224)
#define NB_CVT  6250       // 2 x 3125
#define NB_W    5

#define TBLK    3125       // 16-row tiles per half (50000/16 exact)
#define LDA     136        // padded LDS row stride (ushorts); 272 B, 16B-aligned

typedef __attribute__((ext_vector_type(8))) short short8;
typedef __attribute__((ext_vector_type(4))) float f32x4;

// ---------- bf16 helpers ----------
__device__ __forceinline__ unsigned short f2bf(float f) {
  unsigned u = __float_as_uint(f);
  return (unsigned short)((u + 0x7fffu + ((u >> 16) & 1u)) >> 16);
}
__device__ __forceinline__ float bflo(unsigned u) { return __uint_as_float(u << 16); }
__device__ __forceinline__ float bfhi(unsigned u) { return __uint_as_float(u & 0xffff0000u); }

__device__ __forceinline__ int edge_at(const void* __restrict__ edges, long i, int is64) {
  return is64 ? (int)((const long long*)edges)[i] : ((const int*)edges)[i];
}

// ---------- fused: rel-split LDS-staged partition + x->bf16 cvt + W pack ----------
__global__ __launch_bounds__(256) void part_cvt(
    const void* __restrict__ e0, const void* __restrict__ e1, const void* __restrict__ e2,
    unsigned* __restrict__ part, int* __restrict__ countsT, int* __restrict__ btot,
    const float* __restrict__ xu, const float* __restrict__ xi,
    const float* __restrict__ W_fol, const float* __restrict__ W_bb,
    const float* __restrict__ W_lu, const float* __restrict__ W_buy,
    const float* __restrict__ W_li,
    unsigned short* __restrict__ xu_b, unsigned short* __restrict__ xi_b,
    unsigned short* __restrict__ wfrag) {
  __shared__ unsigned stg[NBUK * SEGCAP];   // 34496 B staging
  __shared__ int scnt[NBUK];
  __shared__ int s_is64;
  int b = blockIdx.x;
  int t = threadIdx.x;
  if (b < NB_PART) {
    int rel = b / KPART;
    int kb = b - rel * KPART;
    if (t < 64) {
      unsigned hi = ((const unsigned*)e0)[2 * t + 1];
      unsigned long long any = __ballot(hi != 0u);
      if (t == 0) s_is64 = (any == 0ull) ? 1 : 0;
    }
    for (int i = t; i < NBUK; i += 256) scnt[i] = 0;
    __syncthreads();
    int is64 = s_is64;
    const void* ep = (rel == 0) ? e0 : (rel == 1) ? e1 : e2;
    int ebase = kb * EPB;
    int eend = min(ebase + EPB, NEDGE);
    for (int ei = ebase + t; ei < eend; ei += 256) {
      int src = edge_at(ep, ei, is64);
      int dst = edge_at(ep, (long)NEDGE + ei, is64);
      int bk = dst >> 8;
      int pos = atomicAdd(&scnt[bk], 1);
      if (pos < SEGCAP)
        stg[bk * SEGCAP + pos] = (unsigned)src | ((unsigned)(dst & 255) << 16);
    }
    __syncthreads();
    const uint4* s4 = (const uint4*)stg;
    uint4* p4 = (uint4*)part;
    for (int i = t; i < NBUK * SEGQ; i += 256) {
      int bk = i / SEGQ, j = i - bk * SEGQ;
      p4[((size_t)((rel * NBUK + bk) * KPART + kb)) * SEGQ + j] = s4[i];
    }
    for (int i = t; i < NBUK; i += 256) {
      int c = min(scnt[i], SEGCAP);
      countsT[(rel * NBUK + i) * KPART + kb] = c;
      atomicAdd(&btot[rel * NBUK + i], c);
    }
  } else if (b < NB_PART + NB_CVT) {
    int cb = b - NB_PART;
    const float* src = (cb < 3125) ? xu : xi;
    unsigned short* dst = (cb < 3125) ? xu_b : xi_b;
    int lb = (cb < 3125) ? cb : cb - 3125;
    size_t base = ((size_t)lb * 256 + t) * 8;
    float4 v0 = *reinterpret_cast<const float4*>(src + base);
    float4 v1 = *reinterpret_cast<const float4*>(src + base + 4);
    uint4 o;
    o.x = f2bf(v0.x) | ((unsigned)f2bf(v0.y) << 16);
    o.y = f2bf(v0.z) | ((unsigned)f2bf(v0.w) << 16);
    o.z = f2bf(v1.x) | ((unsigned)f2bf(v1.y) << 16);
    o.w = f2bf(v1.z) | ((unsigned)f2bf(v1.w) << 16);
    *reinterpret_cast<uint4*>(dst + base) = o;
  } else {
    int s = b - (NB_PART + NB_CVT);
    const float* W = (s == 0) ? W_fol : (s == 1) ? W_bb : (s == 2) ? W_lu
                    : (s == 3) ? W_buy : W_li;
    for (int idx = t; idx < 16384; idx += 256) {
      int k = idx >> 7, n = idx & 127;
      int kc = k >> 5, q = (k >> 3) & 3, j = k & 7;
      int nt = n >> 4, nl = n & 15;
      wfrag[((((size_t)s * 4 + kc) * 8 + nt) * 64 + (q * 16 + nl)) * 8 + j] = f2bf(W[idx]);
    }
  }
}

// ---------- block scan helper ----------
__device__ __forceinline__ int block_scan_incl(int v, int* wsum) {
  int lane = threadIdx.x & 63, wid = threadIdx.x >> 6;
#pragma unroll
  for (int d = 1; d < 64; d <<= 1) {
    int n = __shfl_up(v, d, 64);
    if (lane >= d) v += n;
  }
  if (lane == 63) wsum[wid] = v;
  __syncthreads();
  if (threadIdx.x < 4) {
    int s = wsum[threadIdx.x];
#pragma unroll
    for (int d = 1; d < 4; d <<= 1) {
      int n = __shfl_up(s, d, 64);
      if ((int)threadIdx.x >= d) s += n;
    }
    wsum[threadIdx.x] = s;
  }
  __syncthreads();
  return v + (wid ? wsum[wid - 1] : 0);
}

// ---------- per-bucket CSR build ----------
__global__ __launch_bounds__(256) void csr_build(
    const unsigned* __restrict__ part, const int* __restrict__ countsT,
    const int* __restrict__ btot,
    int* __restrict__ csr0, int* __restrict__ csr1, int* __restrict__ csr2,
    int* __restrict__ rp0, int* __restrict__ rp1, int* __restrict__ rp2) {
  __shared__ int segcnt[256];
  __shared__ int segoff[256];
  __shared__ int wsum[4];
  __shared__ int nTot;
  __shared__ int sBase;
  __shared__ unsigned stage[BUKCAP];     // 16 KB
  __shared__ int cnt[256];
  __shared__ int curs[256];
  __shared__ unsigned short img[BUKCAP]; // 8 KB
  int blk = blockIdx.x;
  int rel = blk / NBUK, lb = blk - rel * NBUK;
  int* __restrict__ csr = (rel == 0) ? csr0 : (rel == 1) ? csr1 : csr2;
  int* __restrict__ rp  = (rel == 0) ? rp0  : (rel == 1) ? rp1  : rp2;
  int t = threadIdx.x;

  int c = (t < KPART) ? countsT[(size_t)blk * KPART + t] : 0;  // issue early
  int bt = (t < NBUK) ? btot[rel * NBUK + t] : 0;
  int cB = min(bt, BUKCAP);
  int inclB = block_scan_incl(cB, wsum);
  if (t == lb) sBase = inclB - cB;
  if (lb == 0 && t == 0) rp[N_NODES] = NEDGE;
  __syncthreads();
  int base = sBase;

  int incl = block_scan_incl(c, wsum);
  segcnt[t] = c;
  segoff[t] = incl - c;
  if (t == 255) nTot = incl;
  __syncthreads();
  int n = min(nTot, BUKCAP);

  const unsigned* __restrict__ reg = part + (size_t)blk * KPART * SEGCAP;
  for (int i = t; i < KPART * SEGCAP; i += 256) {
    int k = i / SEGCAP, j = i - k * SEGCAP;
    if (j < segcnt[k]) stage[segoff[k] + j] = reg[i];
  }
  cnt[t] = 0;
  __syncthreads();

  for (int i = t; i < n; i += 256)
    atomicAdd(&cnt[(stage[i] >> 16) & 255], 1);
  __syncthreads();
  int c2 = cnt[t];
  int incl2 = block_scan_incl(c2, wsum);
  int excl2 = incl2 - c2;
  curs[t] = excl2;
  int d = lb * 256 + t;
  if (d < N_NODES) rp[d] = base + excl2;
  __syncthreads();

  for (int i = t; i < n; i += 256) {
    unsigned en = stage[i];
    int pos = atomicAdd(&curs[(en >> 16) & 255], 1);
    img[pos] = (unsigned short)(en & 0xffffu);
  }
  __syncthreads();
  for (int i = t; i < n; i += 256)
    csr[base + i] = (int)img[i];
}

// ---------- fused agg+GEMM device helpers ----------
__device__ __forceinline__ void stage_gather(
    const int* __restrict__ rp, const int* __restrict__ csr,
    const unsigned short* __restrict__ xs, unsigned short* __restrict__ buf,
    int g0, int w, int sub, int slot) {
  const uint4* __restrict__ xv = (const uint4*)xs;
  for (int ri = 0; ri < 4; ++ri) {
    int r = w * 4 + ri;
    int row = g0 + r;
    int beg = rp[row], end = rp[row + 1];
    float a0 = 0, a1 = 0, a2 = 0, a3 = 0, a4 = 0, a5 = 0, a6 = 0, a7 = 0;
#define ACC8(v) { \
    a0 += bflo(v.x); a1 += bfhi(v.x); \
    a2 += bflo(v.y); a3 += bfhi(v.y); \
    a4 += bflo(v.z); a5 += bfhi(v.z); \
    a6 += bflo(v.w); a7 += bfhi(v.w); }
    for (int e = beg + slot; e < end; e += 16) {
      int i0 = csr[e];
      uint4 v0 = xv[(size_t)i0 * 16 + sub];
      if (e + 4 < end) {
        int i1 = csr[e + 4];
        uint4 v1 = xv[(size_t)i1 * 16 + sub];
        if (e + 8 < end) {
          int i2 = csr[e + 8];
          uint4 v2 = xv[(size_t)i2 * 16 + sub];
          if (e + 12 < end) {
            int i3 = csr[e + 12];
            uint4 v3 = xv[(size_t)i3 * 16 + sub];
            ACC8(v3);
          }
          ACC8(v2);
        }
        ACC8(v1);
      }
      ACC8(v0);
    }
#undef ACC8
#define RED16_32(a) { a += __shfl_xor(a, 16, 64); a += __shfl_xor(a, 32, 64); }
    RED16_32(a0) RED16_32(a1) RED16_32(a2) RED16_32(a3)
    RED16_32(a4) RED16_32(a5) RED16_32(a6) RED16_32(a7)
#undef RED16_32
    if (slot == 0) {
      float rd = 1.0f / fmaxf((float)(end - beg), 1.0f);
      uint4 o;
      o.x = (unsigned)f2bf(a0 * rd) | ((unsigned)f2bf(a1 * rd) << 16);
      o.y = (unsigned)f2bf(a2 * rd) | ((unsigned)f2bf(a3 * rd) << 16);
      o.z = (unsigned)f2bf(a4 * rd) | ((unsigned)f2bf(a5 * rd) << 16);
      o.w = (unsigned)f2bf(a6 * rd) | ((unsigned)f2bf(a7 * rd) << 16);
      *reinterpret_cast<uint4*>(&buf[r * LDA + sub * 8]) = o;
    }
  }
}

__device__ __forceinline__ void stage_self(
    const unsigned short* __restrict__ xs, unsigned short* __restrict__ buf,
    int g0, int w, int sub, int slot) {
  int r = w * 4 + slot;
  uint4 v = *reinterpret_cast<const uint4*>(xs + (size_t)(g0 + r) * FEAT + sub * 8);
  *reinterpret_cast<uint4*>(&buf[r * LDA + sub * 8]) = v;
}

__device__ __forceinline__ void mfma8(
    const unsigned short* __restrict__ buf, const unsigned short* __restrict__ wf,
    f32x4 acc[2], int lane, int w) {
#pragma unroll
  for (int kc = 0; kc < 4; ++kc) {
    short8 afr = *reinterpret_cast<const short8*>(
        &buf[(lane & 15) * LDA + kc * 32 + (lane >> 4) * 8]);
#pragma unroll
    for (int ct = 0; ct < 2; ++ct) {
      int nt = 2 * w + ct;
      short8 bfr = *reinterpret_cast<const short8*>(wf + ((kc * 8 + nt) * 64 + lane) * 8);
      acc[ct] = __builtin_amdgcn_mfma_f32_16x16x32_bf16(afr, bfr, acc[ct], 0, 0, 0);
    }
  }
}

// ---------- FUSED gather-mean aggregation + MFMA GEMM, 16-row tiles ----------
// R9: double-buffered Asp + software pipeline -- region s = {stage source s+1
// into buf[(s+1)&1]  ||  MFMA source s from buf[s&1]}, ONE barrier per region
// (was 2 per source). Barriers: user 6->4, item 4->3; the MFMA+wfrag reads
// now share a region with the next gather instead of a sync-bounded phase.
__global__ __launch_bounds__(256) void agg_gemm16(
    const unsigned short* __restrict__ xu_b, const unsigned short* __restrict__ xi_b,
    const int* __restrict__ rp0, const int* __restrict__ rp1, const int* __restrict__ rp2,
    const int* __restrict__ csr0, const int* __restrict__ csr1, const int* __restrict__ csr2,
    const unsigned short* __restrict__ wfrag,
    const float* __restrict__ b_lu, const float* __restrict__ b_li,
    float* __restrict__ out) {
  __shared__ unsigned short Asp[2][16 * LDA];   // 2 x 4352 B
  const int b = blockIdx.x;
  const int t = threadIdx.x;
  const int half = (b >= TBLK) ? 1 : 0;
  const int g0 = (half ? b - TBLK : b) * 16;
  const int lane = t & 63;
  const int w = t >> 6;
  const int sub = lane & 15, slot = lane >> 4;
  const unsigned short* wf0 = wfrag;                      // follows   (user s0)
  const unsigned short* wf1 = wfrag + 1 * 16384;          // bought_by (user s1)
  const unsigned short* wf2 = wfrag + 2 * 16384;          // loop_user (user s2)
  const unsigned short* wf3 = wfrag + 3 * 16384;          // buys      (item s0)
  const unsigned short* wf4 = wfrag + 4 * 16384;          // loop_item (item s1)

  f32x4 acc[2] = {};

  if (!half) {
    stage_gather(rp0, csr0, xu_b, Asp[0], g0, w, sub, slot);
    __syncthreads();
    stage_gather(rp1, csr1, xi_b, Asp[1], g0, w, sub, slot);
    mfma8(Asp[0], wf0, acc, lane, w);
    __syncthreads();
    stage_self(xu_b, Asp[0], g0, w, sub, slot);
    mfma8(Asp[1], wf1, acc, lane, w);
    __syncthreads();
    mfma8(Asp[0], wf2, acc, lane, w);
  } else {
    stage_gather(rp2, csr2, xu_b, Asp[0], g0, w, sub, slot);
    __syncthreads();
    stage_self(xi_b, Asp[1], g0, w, sub, slot);
    mfma8(Asp[0], wf3, acc, lane, w);
    __syncthreads();
    mfma8(Asp[1], wf4, acc, lane, w);
  }

  // epilogue: bias + relu + store (C/D: col=lane&15, row=(lane>>4)*4+reg)
  const float* bias = half ? b_li : b_lu;
  int q = lane >> 4, nl = lane & 15;
  float bv[2] = { bias[w * 32 + nl], bias[w * 32 + 16 + nl] };
#pragma unroll
  for (int r = 0; r < 4; ++r) {
    size_t orow = (size_t)(half ? N_NODES : 0) + g0 + q * 4 + r;
#pragma unroll
    for (int ct = 0; ct < 2; ++ct) {
      float v = acc[ct][r] + bv[ct];
      out[orow * FEAT + w * 32 + ct * 16 + nl] = fmaxf(v, 0.f);
    }
  }
}

extern "C" void kernel_launch(void* const* d_in, const int* in_sizes, int n_in,
                              void* d_out, int out_size, void* d_ws, size_t ws_size,
                              hipStream_t stream) {
  const float* x_user = (const float*)d_in[0];
  const float* x_item = (const float*)d_in[1];
  const void* e_fol = d_in[2];
  const void* e_buy = d_in[3];
  const void* e_bb  = d_in[4];
  const float* W_fol = (const float*)d_in[5];
  const float* W_buy = (const float*)d_in[6];
  const float* W_bb  = (const float*)d_in[7];
  const float* W_lu  = (const float*)d_in[8];
  const float* b_lu  = (const float*)d_in[9];
  const float* W_li  = (const float*)d_in[10];
  const float* b_li  = (const float*)d_in[11];
  float* out = (float*)d_out;

  // ws: part (23.2 MB) at base; bf16 x / wfrag above; ints at +64 MB.
  unsigned short* wsu = (unsigned short*)d_ws;
  unsigned short* xu_b  = wsu + 19200000;
  unsigned short* xi_b  = wsu + 25600000;
  unsigned short* wfrag = wsu + 32000000;      // 81920 ushorts
  unsigned* part = (unsigned*)d_ws;            // NBUKT*KPART*SEGCAP = 5,795,328 uints
  int* ip = (int*)d_ws + 16040960;
  int* csr0 = ip;
  int* csr1 = ip + 600000;
  int* csr2 = ip + 1200000;
  int* rp0  = ip + 1800000;     // 50016 each
  int* rp1  = rp0 + 50016;
  int* rp2  = rp1 + 50016;
  int* countsT = ip + 1950048;  // NBUKT*KPART = 131712
  int* btot    = ip + 2081760;  // 588

  hipMemsetAsync(btot, 0, NBUKT * sizeof(int), stream);

  // rel order preserved: rel0=follows, rel1=bought_by, rel2=buys
  part_cvt<<<NB_PART + NB_CVT + NB_W, 256, 0, stream>>>(
      e_fol, e_bb, e_buy, part, countsT, btot, x_user, x_item,
      W_fol, W_bb, W_lu, W_buy, W_li, xu_b, xi_b, wfrag);

  csr_build<<<3 * NBUK, 256, 0, stream>>>(part, countsT, btot,
                                          csr0, csr1, csr2, rp0, rp1, rp2);

  agg_gemm16<<<2 * TBLK, 256, 0, stream>>>(
      xu_b, xi_b, rp0, rp1, rp2, csr0, csr1, csr2,
      wfrag, b_lu, b_li, out);
}

// Round 10
// 252.302 us; speedup vs baseline: 1.0491x; 1.0491x over previous
//
#include <hip/hip_runtime.h>

#define N_NODES 50000
#define FEAT    128
#define NEDGE   600000

#define NBUK    196        // buckets per rel (256 dsts each); 588 total
#define NBUKT   588
#define BUKCAP  4096       // bucket total: mean 3061, sigma 55 -> 19 sigma
#define KPART   224        // partition slices per rel
#define NB_PART 672        // 3 rels x KPART, one rel per block
#define SEGCAP  44         // mean 13.7; Poisson tail @44 ~ 4e-11/seg, 5e-6 overall
#define SEGQ    11         // SEGCAP/4 uint4s
#define EPB     2679       // ceil(600000/224)
#define NB_CVT  6250       // 2 x 3125
#define NB_W    5

#define TBLK    3125       // 16-row tiles per half (50000/16 exact)
#define LDA     136        // padded LDS row stride (ushorts); 272 B, 16B-aligned

typedef __attribute__((ext_vector_type(8))) short short8;
typedef __attribute__((ext_vector_type(4))) float f32x4;

// ---------- bf16 helpers ----------
__device__ __forceinline__ unsigned short f2bf(float f) {
  unsigned u = __float_as_uint(f);
  return (unsigned short)((u + 0x7fffu + ((u >> 16) & 1u)) >> 16);
}
__device__ __forceinline__ float bflo(unsigned u) { return __uint_as_float(u << 16); }
__device__ __forceinline__ float bfhi(unsigned u) { return __uint_as_float(u & 0xffff0000u); }

__device__ __forceinline__ int edge_at(const void* __restrict__ edges, long i, int is64) {
  return is64 ? (int)((const long long*)edges)[i] : ((const int*)edges)[i];
}

// ---------- fused: rel-split LDS-staged partition + x->bf16 cvt + W pack ----------
// Partition: ONE rel per block (672 blocks) -> 3x critical-path parallelism
// vs the old 224-blocks x 3-serial-passes form. Segments staged in LDS,
// flushed as contiguous uint4 runs.
// part layout TRANSPOSED: part[((rel*NBUK+bucket)*KPART + kb)*SEGCAP + pos]
// -> a bucket's 224 segments are one contiguous ~39 KB region for csr_build.
__global__ __launch_bounds__(256) void part_cvt(
    const void* __restrict__ e0, const void* __restrict__ e1, const void* __restrict__ e2,
    unsigned* __restrict__ part, int* __restrict__ countsT, int* __restrict__ btot,
    const float* __restrict__ xu, const float* __restrict__ xi,
    const float* __restrict__ W_fol, const float* __restrict__ W_bb,
    const float* __restrict__ W_lu, const float* __restrict__ W_buy,
    const float* __restrict__ W_li,
    unsigned short* __restrict__ xu_b, unsigned short* __restrict__ xi_b,
    unsigned short* __restrict__ wfrag) {
  __shared__ unsigned stg[NBUK * SEGCAP];   // 34496 B staging
  __shared__ int scnt[NBUK];
  __shared__ int s_is64;
  int b = blockIdx.x;
  int t = threadIdx.x;
  if (b < NB_PART) {
    int rel = b / KPART;
    int kb = b - rel * KPART;
    // inline dtype detect: wave 0 samples the first 64 u32-pair hi words
    if (t < 64) {
      unsigned hi = ((const unsigned*)e0)[2 * t + 1];
      unsigned long long any = __ballot(hi != 0u);
      if (t == 0) s_is64 = (any == 0ull) ? 1 : 0;
    }
    for (int i = t; i < NBUK; i += 256) scnt[i] = 0;
    __syncthreads();
    int is64 = s_is64;
    const void* ep = (rel == 0) ? e0 : (rel == 1) ? e1 : e2;
    int ebase = kb * EPB;
    int eend = min(ebase + EPB, NEDGE);
    for (int ei = ebase + t; ei < eend; ei += 256) {
      int src = edge_at(ep, ei, is64);
      int dst = edge_at(ep, (long)NEDGE + ei, is64);
      int bk = dst >> 8;
      int pos = atomicAdd(&scnt[bk], 1);
      if (pos < SEGCAP)
        stg[bk * SEGCAP + pos] = (unsigned)src | ((unsigned)(dst & 255) << 16);
    }
    __syncthreads();
    // coalesced flush: full segments (stale tail entries bounded by countsT)
    const uint4* s4 = (const uint4*)stg;
    uint4* p4 = (uint4*)part;
    for (int i = t; i < NBUK * SEGQ; i += 256) {
      int bk = i / SEGQ, j = i - bk * SEGQ;
      p4[((size_t)((rel * NBUK + bk) * KPART + kb)) * SEGQ + j] = s4[i];
    }
    for (int i = t; i < NBUK; i += 256) {
      int c = min(scnt[i], SEGCAP);
      countsT[(rel * NBUK + i) * KPART + kb] = c;
      atomicAdd(&btot[rel * NBUK + i], c);   // cross-block totals (pre-zeroed)
    }
  } else if (b < NB_PART + NB_CVT) {
    int cb = b - NB_PART;
    const float* src = (cb < 3125) ? xu : xi;
    unsigned short* dst = (cb < 3125) ? xu_b : xi_b;
    int lb = (cb < 3125) ? cb : cb - 3125;
    size_t base = ((size_t)lb * 256 + t) * 8;
    float4 v0 = *reinterpret_cast<const float4*>(src + base);
    float4 v1 = *reinterpret_cast<const float4*>(src + base + 4);
    uint4 o;
    o.x = f2bf(v0.x) | ((unsigned)f2bf(v0.y) << 16);
    o.y = f2bf(v0.z) | ((unsigned)f2bf(v0.w) << 16);
    o.z = f2bf(v1.x) | ((unsigned)f2bf(v1.y) << 16);
    o.w = f2bf(v1.z) | ((unsigned)f2bf(v1.w) << 16);
    *reinterpret_cast<uint4*>(dst + base) = o;
  } else {
    int s = b - (NB_PART + NB_CVT);
    const float* W = (s == 0) ? W_fol : (s == 1) ? W_bb : (s == 2) ? W_lu
                    : (s == 3) ? W_buy : W_li;
    for (int idx = t; idx < 16384; idx += 256) {
      int k = idx >> 7, n = idx & 127;
      int kc = k >> 5, q = (k >> 3) & 3, j = k & 7;
      int nt = n >> 4, nl = n & 15;
      wfrag[((((size_t)s * 4 + kc) * 8 + nt) * 64 + (q * 16 + nl)) * 8 + j] = f2bf(W[idx]);
    }
  }
}

// ---------- block scan helper ----------
__device__ __forceinline__ int block_scan_incl(int v, int* wsum) {
  int lane = threadIdx.x & 63, wid = threadIdx.x >> 6;
#pragma unroll
  for (int d = 1; d < 64; d <<= 1) {
    int n = __shfl_up(v, d, 64);
    if (lane >= d) v += n;
  }
  if (lane == 63) wsum[wid] = v;
  __syncthreads();
  if (threadIdx.x < 4) {
    int s = wsum[threadIdx.x];
#pragma unroll
    for (int d = 1; d < 4; d <<= 1) {
      int n = __shfl_up(s, d, 64);
      if ((int)threadIdx.x >= d) s += n;
    }
    wsum[threadIdx.x] = s;
  }
  __syncthreads();
  return v + (wid ? wsum[wid - 1] : 0);
}

// ---------- per-bucket CSR build ----------
__global__ __launch_bounds__(256) void csr_build(
    const unsigned* __restrict__ part, const int* __restrict__ countsT,
    const int* __restrict__ btot,
    int* __restrict__ csr0, int* __restrict__ csr1, int* __restrict__ csr2,
    int* __restrict__ rp0, int* __restrict__ rp1, int* __restrict__ rp2) {
  __shared__ int segcnt[256];
  __shared__ int segoff[256];
  __shared__ int wsum[4];
  __shared__ int nTot;
  __shared__ int sBase;
  __shared__ unsigned stage[BUKCAP];     // 16 KB
  __shared__ int cnt[256];
  __shared__ int curs[256];
  __shared__ unsigned short img[BUKCAP]; // 8 KB
  int blk = blockIdx.x;
  int rel = blk / NBUK, lb = blk - rel * NBUK;
  int* __restrict__ csr = (rel == 0) ? csr0 : (rel == 1) ? csr1 : csr2;
  int* __restrict__ rp  = (rel == 0) ? rp0  : (rel == 1) ? rp1  : rp2;
  int t = threadIdx.x;

  int c = (t < KPART) ? countsT[(size_t)blk * KPART + t] : 0;  // issue early
  int bt = (t < NBUK) ? btot[rel * NBUK + t] : 0;
  int cB = min(bt, BUKCAP);
  int inclB = block_scan_incl(cB, wsum);
  if (t == lb) sBase = inclB - cB;
  if (lb == 0 && t == 0) rp[N_NODES] = NEDGE;
  __syncthreads();
  int base = sBase;

  int incl = block_scan_incl(c, wsum);
  segcnt[t] = c;
  segoff[t] = incl - c;
  if (t == 255) nTot = incl;
  __syncthreads();
  int n = min(nTot, BUKCAP);

  const unsigned* __restrict__ reg = part + (size_t)blk * KPART * SEGCAP;
  for (int i = t; i < KPART * SEGCAP; i += 256) {
    int k = i / SEGCAP, j = i - k * SEGCAP;
    if (j < segcnt[k]) stage[segoff[k] + j] = reg[i];
  }
  cnt[t] = 0;
  __syncthreads();

  for (int i = t; i < n; i += 256)
    atomicAdd(&cnt[(stage[i] >> 16) & 255], 1);
  __syncthreads();
  int c2 = cnt[t];
  int incl2 = block_scan_incl(c2, wsum);
  int excl2 = incl2 - c2;
  curs[t] = excl2;
  int d = lb * 256 + t;
  if (d < N_NODES) rp[d] = base + excl2;
  __syncthreads();

  for (int i = t; i < n; i += 256) {
    unsigned en = stage[i];
    int pos = atomicAdd(&curs[(en >> 16) & 255], 1);
    img[pos] = (unsigned short)(en & 0xffffu);
  }
  __syncthreads();
  for (int i = t; i < n; i += 256)
    csr[base + i] = (int)img[i];
}

// ---------- FUSED gather-mean aggregation + MFMA GEMM, 16-row tiles ----------
// (R8 structure -- verified best. 6250 blocks x 4 waves; R4 intra-row gather
// pattern; padded row-major LDS stage; 8 MFMAs/wave/source on idle matrix
// pipes; 2 cheap barriers per source. R9's merged-region pipeline REGRESSED:
// +8 VGPR, occupancy 66->50%, gather scheduling degraded -- reverted.)
__global__ __launch_bounds__(256) void agg_gemm16(
    const unsigned short* __restrict__ xu_b, const unsigned short* __restrict__ xi_b,
    const int* __restrict__ rp0, const int* __restrict__ rp1, const int* __restrict__ rp2,
    const int* __restrict__ csr0, const int* __restrict__ csr1, const int* __restrict__ csr2,
    const unsigned short* __restrict__ wfrag,
    const float* __restrict__ b_lu, const float* __restrict__ b_li,
    float* __restrict__ out) {
  __shared__ unsigned short Asp[16 * LDA];   // 4352 B
  const int b = blockIdx.x;
  const int t = threadIdx.x;
  const int half = (b >= TBLK) ? 1 : 0;
  const int g0 = (half ? b - TBLK : b) * 16;
  const int lane = t & 63;
  const int w = t >> 6;
  const int sub = lane & 15, slot = lane >> 4;
  const int nsrc = half ? 2 : 3;
  const int widx0 = half ? 3 : 0;

  f32x4 acc[2] = {};

  for (int s = 0; s < nsrc; ++s) {
    if (s == nsrc - 1) {
      // self-loop source: direct vectorized stage (4 rows/wave, 16B/lane)
      const unsigned short* xs = half ? xi_b : xu_b;
      int r = w * 4 + slot;
      uint4 v = *reinterpret_cast<const uint4*>(xs + (size_t)(g0 + r) * FEAT + sub * 8);
      *reinterpret_cast<uint4*>(&Asp[r * LDA + sub * 8]) = v;
    } else {
      const int* rp; const int* csr; const unsigned short* xs;
      if (!half) {
        if (s == 0) { rp = rp0; csr = csr0; xs = xu_b; }
        else        { rp = rp1; csr = csr1; xs = xi_b; }
      } else        { rp = rp2; csr = csr2; xs = xu_b; }
      const uint4* __restrict__ xv = (const uint4*)xs;
      for (int ri = 0; ri < 4; ++ri) {
        int r = w * 4 + ri;
        int row = g0 + r;
        int beg = rp[row], end = rp[row + 1];
        float a0 = 0, a1 = 0, a2 = 0, a3 = 0, a4 = 0, a5 = 0, a6 = 0, a7 = 0;
#define ACC8(v) { \
    a0 += bflo(v.x); a1 += bfhi(v.x); \
    a2 += bflo(v.y); a3 += bfhi(v.y); \
    a4 += bflo(v.z); a5 += bfhi(v.z); \
    a6 += bflo(v.w); a7 += bfhi(v.w); }
        for (int e = beg + slot; e < end; e += 16) {
          int i0 = csr[e];
          uint4 v0 = xv[(size_t)i0 * 16 + sub];
          if (e + 4 < end) {
            int i1 = csr[e + 4];
            uint4 v1 = xv[(size_t)i1 * 16 + sub];
            if (e + 8 < end) {
              int i2 = csr[e + 8];
              uint4 v2 = xv[(size_t)i2 * 16 + sub];
              if (e + 12 < end) {
                int i3 = csr[e + 12];
                uint4 v3 = xv[(size_t)i3 * 16 + sub];
                ACC8(v3);
              }
              ACC8(v2);
            }
            ACC8(v1);
          }
          ACC8(v0);
        }
#undef ACC8
#define RED16_32(a) { a += __shfl_xor(a, 16, 64); a += __shfl_xor(a, 32, 64); }
        RED16_32(a0) RED16_32(a1) RED16_32(a2) RED16_32(a3)
        RED16_32(a4) RED16_32(a5) RED16_32(a6) RED16_32(a7)
#undef RED16_32
        if (slot == 0) {
          float rd = 1.0f / fmaxf((float)(end - beg), 1.0f);
          uint4 o;
          o.x = (unsigned)f2bf(a0 * rd) | ((unsigned)f2bf(a1 * rd) << 16);
          o.y = (unsigned)f2bf(a2 * rd) | ((unsigned)f2bf(a3 * rd) << 16);
          o.z = (unsigned)f2bf(a4 * rd) | ((unsigned)f2bf(a5 * rd) << 16);
          o.w = (unsigned)f2bf(a6 * rd) | ((unsigned)f2bf(a7 * rd) << 16);
          *reinterpret_cast<uint4*>(&Asp[r * LDA + sub * 8]) = o;
        }
      }
    }
    __syncthreads();
    // GEMM accumulate: A-frag from padded row-major LDS, B-frag from wfrag
    const unsigned short* wf = wfrag + (size_t)(widx0 + s) * (4 * 8 * 64 * 8);
#pragma unroll
    for (int kc = 0; kc < 4; ++kc) {
      short8 afr = *reinterpret_cast<const short8*>(
          &Asp[(lane & 15) * LDA + kc * 32 + (lane >> 4) * 8]);
#pragma unroll
      for (int ct = 0; ct < 2; ++ct) {
        int nt = 2 * w + ct;
        short8 bfr = *reinterpret_cast<const short8*>(wf + ((kc * 8 + nt) * 64 + lane) * 8);
        acc[ct] = __builtin_amdgcn_mfma_f32_16x16x32_bf16(afr, bfr, acc[ct], 0, 0, 0);
      }
    }
    __syncthreads();
  }

  // epilogue: bias + relu + store (C/D: col=lane&15, row=(lane>>4)*4+reg)
  const float* bias = half ? b_li : b_lu;
  int q = lane >> 4, nl = lane & 15;
  float bv[2] = { bias[w * 32 + nl], bias[w * 32 + 16 + nl] };
#pragma unroll
  for (int r = 0; r < 4; ++r) {
    size_t orow = (size_t)(half ? N_NODES : 0) + g0 + q * 4 + r;
#pragma unroll
    for (int ct = 0; ct < 2; ++ct) {
      float v = acc[ct][r] + bv[ct];
      out[orow * FEAT + w * 32 + ct * 16 + nl] = fmaxf(v, 0.f);
    }
  }
}

extern "C" void kernel_launch(void* const* d_in, const int* in_sizes, int n_in,
                              void* d_out, int out_size, void* d_ws, size_t ws_size,
                              hipStream_t stream) {
  const float* x_user = (const float*)d_in[0];
  const float* x_item = (const float*)d_in[1];
  const void* e_fol = d_in[2];
  const void* e_buy = d_in[3];
  const void* e_bb  = d_in[4];
  const float* W_fol = (const float*)d_in[5];
  const float* W_buy = (const float*)d_in[6];
  const float* W_bb  = (const float*)d_in[7];
  const float* W_lu  = (const float*)d_in[8];
  const float* b_lu  = (const float*)d_in[9];
  const float* W_li  = (const float*)d_in[10];
  const float* b_li  = (const float*)d_in[11];
  float* out = (float*)d_out;

  // ws: part (23.2 MB) at base; bf16 x / wfrag above; ints at +64 MB.
  unsigned short* wsu = (unsigned short*)d_ws;
  unsigned short* xu_b  = wsu + 19200000;
  unsigned short* xi_b  = wsu + 25600000;
  unsigned short* wfrag = wsu + 32000000;      // 81920 ushorts
  unsigned* part = (unsigned*)d_ws;            // NBUKT*KPART*SEGCAP = 5,795,328 uints
  int* ip = (int*)d_ws + 16040960;
  int* csr0 = ip;
  int* csr1 = ip + 600000;
  int* csr2 = ip + 1200000;
  int* rp0  = ip + 1800000;     // 50016 each
  int* rp1  = rp0 + 50016;
  int* rp2  = rp1 + 50016;
  int* countsT = ip + 1950048;  // NBUKT*KPART = 131712
  int* btot    = ip + 2081760;  // 588

  hipMemsetAsync(btot, 0, NBUKT * sizeof(int), stream);

  // rel order preserved: rel0=follows, rel1=bought_by, rel2=buys
  part_cvt<<<NB_PART + NB_CVT + NB_W, 256, 0, stream>>>(
      e_fol, e_bb, e_buy, part, countsT, btot, x_user, x_item,
      W_fol, W_bb, W_lu, W_buy, W_li, xu_b, xi_b, wfrag);

  csr_build<<<3 * NBUK, 256, 0, stream>>>(part, countsT, btot,
                                          csr0, csr1, csr2, rp0, rp1, rp2);

  agg_gemm16<<<2 * TBLK, 256, 0, stream>>>(
      xu_b, xi_b, rp0, rp1, rp2, csr0, csr1, csr2,
      wfrag, b_lu, b_li, out);
}